// Round 1
// 337.163 us; speedup vs baseline: 1.0785x; 1.0785x over previous
//
#include <hip/hip_runtime.h>

#define N_NODES 100000
#define N_EDGES 1600000
#define NB 391                 // buckets of 256 nodes: bucket = dst >> 8
#define PAD 16                 // pad atomic counters to one 64B line each
#define SC_EPB 2048            // edges per scatter block
#define SC_BLOCKS ((N_EDGES + SC_EPB - 1) / SC_EPB)   // 782
#define LDA 136                // LDS row stride in bf16 (128 + 8 pad)
#define NTILES ((N_NODES + 127) / 128)                // 782

typedef unsigned int uint32;
typedef __attribute__((ext_vector_type(8))) short bf16x8;
typedef __attribute__((ext_vector_type(4))) float f32x4;

// bf16 round-to-nearest-even helpers
__device__ __forceinline__ uint32 bf16_rne(float f) {
    uint32 u = __float_as_uint(f);
    return (u + 0x7fffu + ((u >> 16) & 1u)) >> 16;
}
__device__ __forceinline__ uint32 pack_bf16x2(float lo, float hi) {
    return bf16_rne(lo) | (bf16_rne(hi) << 16);
}
__device__ __forceinline__ float bf16_lo(uint32 u) { return __uint_as_float(u << 16); }
__device__ __forceinline__ float bf16_hi(uint32 u) { return __uint_as_float(u & 0xFFFF0000u); }

// ===========================================================================
// x [N,128] f32 -> packed bf16 (one uint32 = 2 features)
// ===========================================================================
__global__ __launch_bounds__(256) void conv_x(const float* __restrict__ x,
                                              uint32* __restrict__ xb) {
    const int t = blockIdx.x * 256 + threadIdx.x;   // over N*64
    if (t >= N_NODES * 64) return;
    const float2 v = ((const float2*)x)[t];
    xb[t] = pack_bf16x2(v.x, v.y);
}

// W1 [128,128] -> W1T bf16 [n=128][k=128]; W2 [128,64] -> W2T bf16 [n=64][k=128]
__global__ __launch_bounds__(256) void conv_w(const float* __restrict__ W1,
                                              const float* __restrict__ W2,
                                              uint32* __restrict__ w1tb,
                                              uint32* __restrict__ w2tb) {
    const int t = blockIdx.x * 256 + threadIdx.x;
    if (t < 128 * 64) {
        const int n = t >> 6, kk = t & 63;
        w1tb[t] = pack_bf16x2(W1[(2 * kk) * 128 + n], W1[(2 * kk + 1) * 128 + n]);
    } else if (t < 128 * 64 + 64 * 64) {
        const int u = t - 128 * 64;
        const int n = u >> 6, kk = u & 63;
        w2tb[u] = pack_bf16x2(W2[(2 * kk) * 64 + n], W2[(2 * kk + 1) * 64 + n]);
    }
}

// ===========================================================================
// Bucketed CSR build (unchanged).
// ===========================================================================
__global__ __launch_bounds__(256) void bucket_hist(const int* __restrict__ dst,
                                                   int* __restrict__ bktCnt) {
    __shared__ int h[NB];
    for (int i = threadIdx.x; i < NB; i += 256) h[i] = 0;
    __syncthreads();
    for (int e = blockIdx.x * 256 + threadIdx.x; e < N_EDGES; e += NB * 256)
        atomicAdd(&h[dst[e] >> 8], 1);
    __syncthreads();
    for (int i = threadIdx.x; i < NB; i += 256)
        if (h[i]) atomicAdd(&bktCnt[i * PAD], h[i]);
}

__global__ __launch_bounds__(512) void bucket_scan(const int* __restrict__ bktCnt,
                                                   int* __restrict__ bBase,
                                                   int* __restrict__ bCur,
                                                   int* __restrict__ offs) {
    __shared__ int s[512];
    const int t = threadIdx.x;
    int v = (t < NB) ? bktCnt[t * PAD] : 0;
    s[t] = v;
    __syncthreads();
#pragma unroll
    for (int off = 1; off < 512; off <<= 1) {
        int u = (t >= off) ? s[t - off] : 0;
        __syncthreads();
        s[t] += u;
        __syncthreads();
    }
    if (t < NB) {
        const int excl = s[t] - v;
        bBase[t] = excl;
        bCur[t * PAD] = excl;
    }
    if (t == 0) {
        bBase[NB] = N_EDGES;
        offs[N_NODES] = N_EDGES;
    }
}

__global__ __launch_bounds__(256) void bucket_scatter2(const int* __restrict__ dst,
                                                       const int* __restrict__ src,
                                                       const float* __restrict__ ew,
                                                       int* __restrict__ bCur,
                                                       int2* __restrict__ bucketed) {
    __shared__ int h[NB];
    __shared__ int cur[NB];
    const int base = blockIdx.x * SC_EPB;
    const int end  = min(base + SC_EPB, N_EDGES);

    for (int i = threadIdx.x; i < NB; i += 256) h[i] = 0;
    __syncthreads();
    for (int e = base + threadIdx.x; e < end; e += 256)
        atomicAdd(&h[dst[e] >> 8], 1);
    __syncthreads();
    for (int i = threadIdx.x; i < NB; i += 256) {
        const int c = h[i];
        cur[i] = c ? atomicAdd(&bCur[i * PAD], c) : 0;
    }
    __syncthreads();
    for (int e = base + threadIdx.x; e < end; e += 256) {
        const int d = dst[e];
        const int p = atomicAdd(&cur[d >> 8], 1);   // LDS atomic
        bucketed[p] = make_int2(src[e] | ((d & 255) << 17), __float_as_int(ew[e]));
    }
}

__global__ __launch_bounds__(256) void bucket_csr(const int2* __restrict__ bucketed,
                                                  const int* __restrict__ bBase,
                                                  int* __restrict__ offs,
                                                  int2* __restrict__ csr_ef) {
    __shared__ int sdeg[256];
    __shared__ int lcur[256];
    const int b   = blockIdx.x;
    const int t   = threadIdx.x;
    const int beg = bBase[b], end = bBase[b + 1];

    sdeg[t] = 0;
    __syncthreads();
    for (int j = beg + t; j < end; j += 256)
        atomicAdd(&sdeg[(bucketed[j].x >> 17) & 255], 1);
    __syncthreads();
    const int mydeg = sdeg[t];
#pragma unroll
    for (int off = 1; off < 256; off <<= 1) {
        int u = (t >= off) ? sdeg[t - off] : 0;
        __syncthreads();
        sdeg[t] += u;
        __syncthreads();
    }
    const int excl = sdeg[t] - mydeg;
    lcur[t] = excl;
    const int node = b * 256 + t;
    if (node < N_NODES) offs[node] = beg + excl;
    __syncthreads();

    for (int j = beg + t; j < end; j += 256) {
        const int2 v = bucketed[j];
        const int dl = (v.x >> 17) & 255;
        const int p  = beg + atomicAdd(&lcur[dl], 1);
        csr_ef[p] = make_int2(v.x & 0x1FFFF, v.y);
    }
}

// ===========================================================================
// Gather-aggregate over bf16 feature tables, fp32 accumulate.
// NEW structure: lane-group edge parallelism.
//   FEAT=128: 16 lanes x uint4 cover a 256B row -> 4 edge rows per load inst.
//   FEAT=64 :  8 lanes x uint4 cover a 128B row -> 8 edge rows per load inst.
// Each lane accumulates 8 features of its group's edges; 2-3 shfl_xor steps
// reduce across groups once per node. Unrolled x2 -> 2 KB in flight per wave.
// ===========================================================================
template <int FEAT>
__global__ __launch_bounds__(256) void aggregate(const void* __restrict__ featv,
                                                 const int* __restrict__ offs,
                                                 const int2* __restrict__ csr_ef,
                                                 const float* __restrict__ bias,
                                                 void* __restrict__ outv) {
    const int n    = (blockIdx.x * 256 + threadIdx.x) >> 6;
    const int lane = threadIdx.x & 63;
    if (n >= N_NODES) return;
    const int beg = offs[n], end = offs[n + 1];
    const uint4* feat = (const uint4*)featv;

    float a0 = 0.f, a1 = 0.f, a2 = 0.f, a3 = 0.f;
    float a4 = 0.f, a5 = 0.f, a6 = 0.f, a7 = 0.f;

    if constexpr (FEAT == 128) {
        const int g  = lane >> 4;   // edge slot within quad (0..3)
        const int f8 = lane & 15;   // 8-feature chunk (0..15)

        for (int j = beg + g; j < end; j += 8) {
            {   // quad A (guard is loop condition)
                const int2 e = csr_ef[j];
                const uint4 r = feat[(unsigned)(e.x * 16 + f8)];
                const float w = __int_as_float(e.y);
                a0 += w * bf16_lo(r.x); a1 += w * bf16_hi(r.x);
                a2 += w * bf16_lo(r.y); a3 += w * bf16_hi(r.y);
                a4 += w * bf16_lo(r.z); a5 += w * bf16_hi(r.z);
                a6 += w * bf16_lo(r.w); a7 += w * bf16_hi(r.w);
            }
            if (j + 4 < end) {   // quad B (group-uniform predicate)
                const int2 e = csr_ef[j + 4];
                const uint4 r = feat[(unsigned)(e.x * 16 + f8)];
                const float w = __int_as_float(e.y);
                a0 += w * bf16_lo(r.x); a1 += w * bf16_hi(r.x);
                a2 += w * bf16_lo(r.y); a3 += w * bf16_hi(r.y);
                a4 += w * bf16_lo(r.z); a5 += w * bf16_hi(r.z);
                a6 += w * bf16_lo(r.w); a7 += w * bf16_hi(r.w);
            }
        }

        // reduce across the 4 edge groups (same f8, g differs in bits 4..5)
        a0 += __shfl_xor(a0, 16); a1 += __shfl_xor(a1, 16);
        a2 += __shfl_xor(a2, 16); a3 += __shfl_xor(a3, 16);
        a4 += __shfl_xor(a4, 16); a5 += __shfl_xor(a5, 16);
        a6 += __shfl_xor(a6, 16); a7 += __shfl_xor(a7, 16);
        a0 += __shfl_xor(a0, 32); a1 += __shfl_xor(a1, 32);
        a2 += __shfl_xor(a2, 32); a3 += __shfl_xor(a3, 32);
        a4 += __shfl_xor(a4, 32); a5 += __shfl_xor(a5, 32);
        a6 += __shfl_xor(a6, 32); a7 += __shfl_xor(a7, 32);

        if (g == 0) {
            uint4 p;
            p.x = pack_bf16x2(a0, a1);
            p.y = pack_bf16x2(a2, a3);
            p.z = pack_bf16x2(a4, a5);
            p.w = pack_bf16x2(a6, a7);
            ((uint4*)outv)[(size_t)n * 16 + f8] = p;
        }
    } else {
        const int g  = lane >> 3;   // edge slot within octet (0..7)
        const int f4 = lane & 7;    // 8-feature chunk (0..7)

        for (int j = beg + g; j < end; j += 16) {
            {   // octet A
                const int2 e = csr_ef[j];
                const uint4 r = feat[(unsigned)(e.x * 8 + f4)];
                const float w = __int_as_float(e.y);
                a0 += w * bf16_lo(r.x); a1 += w * bf16_hi(r.x);
                a2 += w * bf16_lo(r.y); a3 += w * bf16_hi(r.y);
                a4 += w * bf16_lo(r.z); a5 += w * bf16_hi(r.z);
                a6 += w * bf16_lo(r.w); a7 += w * bf16_hi(r.w);
            }
            if (j + 8 < end) {   // octet B
                const int2 e = csr_ef[j + 8];
                const uint4 r = feat[(unsigned)(e.x * 8 + f4)];
                const float w = __int_as_float(e.y);
                a0 += w * bf16_lo(r.x); a1 += w * bf16_hi(r.x);
                a2 += w * bf16_lo(r.y); a3 += w * bf16_hi(r.y);
                a4 += w * bf16_lo(r.z); a5 += w * bf16_hi(r.z);
                a6 += w * bf16_lo(r.w); a7 += w * bf16_hi(r.w);
            }
        }

        // reduce across the 8 edge groups (g in bits 3..5)
        a0 += __shfl_xor(a0, 8);  a1 += __shfl_xor(a1, 8);
        a2 += __shfl_xor(a2, 8);  a3 += __shfl_xor(a3, 8);
        a4 += __shfl_xor(a4, 8);  a5 += __shfl_xor(a5, 8);
        a6 += __shfl_xor(a6, 8);  a7 += __shfl_xor(a7, 8);
        a0 += __shfl_xor(a0, 16); a1 += __shfl_xor(a1, 16);
        a2 += __shfl_xor(a2, 16); a3 += __shfl_xor(a3, 16);
        a4 += __shfl_xor(a4, 16); a5 += __shfl_xor(a5, 16);
        a6 += __shfl_xor(a6, 16); a7 += __shfl_xor(a7, 16);
        a0 += __shfl_xor(a0, 32); a1 += __shfl_xor(a1, 32);
        a2 += __shfl_xor(a2, 32); a3 += __shfl_xor(a3, 32);
        a4 += __shfl_xor(a4, 32); a5 += __shfl_xor(a5, 32);
        a6 += __shfl_xor(a6, 32); a7 += __shfl_xor(a7, 32);

        if (g == 0) {
            const float4* b4 = (const float4*)bias;
            const float4 bA = b4[f4 * 2];
            const float4 bB = b4[f4 * 2 + 1];
            float4 o0 = make_float4(a0 + bA.x, a1 + bA.y, a2 + bA.z, a3 + bA.w);
            float4 o1 = make_float4(a4 + bB.x, a5 + bB.y, a6 + bB.z, a7 + bB.w);
            ((float4*)outv)[(size_t)n * 16 + f4 * 2]     = o0;
            ((float4*)outv)[(size_t)n * 16 + f4 * 2 + 1] = o1;
        }
    }
}

// ===========================================================================
// MFMA fused double GEMM: sup2b[N,64](bf16) = relu(aggPb@W1 + b1) @ W2.
// 512 threads = 8 waves; 128-row tile; mfma_f32_16x16x32_bf16.
// STATIC tile distribution (tile = blockIdx.x + k*gridDim.x).
// ===========================================================================
__global__ __launch_bounds__(512) void gemm_fused(const uint32* __restrict__ aggPb,
                                                  const uint32* __restrict__ w1tb,
                                                  const float* __restrict__ b1,
                                                  const uint32* __restrict__ w2tb,
                                                  uint32* __restrict__ sup2b, int N) {
    __shared__ __align__(16) short As[128 * LDA];   // A tile / C bounce
    __shared__ __align__(16) short W1s[128 * LDA];  // W1T [n][k]
    __shared__ __align__(16) short W2s[64 * LDA];   // W2T [n][k]
    __shared__ __align__(16) short Ts[128 * LDA];   // relu intermediate [row][col]

    const int tid = threadIdx.x;

    // Stage W1T/W2T (once per block), coalesced uint4 (8 bf16 each)
    for (int i = tid; i < 128 * 16; i += 512)
        *(uint4*)&W1s[(i >> 4) * LDA + (i & 15) * 8] = ((const uint4*)w1tb)[i];
    for (int i = tid; i < 64 * 16; i += 512)
        *(uint4*)&W2s[(i >> 4) * LDA + (i & 15) * 8] = ((const uint4*)w2tb)[i];

    const int wave = tid >> 6;
    const int lane = tid & 63;
    const int m    = lane & 15;
    const int quad = lane >> 4;
    const int rowbase = (wave & 3) * 32;   // phase A rows (2 substrips of 16)
    const int colbase = (wave >> 2) * 64;  // phase A cols (4 tiles of 16)

    float b1r[4];
#pragma unroll
    for (int ct = 0; ct < 4; ++ct) b1r[ct] = b1[colbase + ct * 16 + m];

    for (int tile = blockIdx.x; tile < NTILES; tile += gridDim.x) {
        const int row0 = tile * 128;
        __syncthreads();   // prev iter's store reads of As done; W staging on first

        // ---- Stage A tile: 128 rows x 16 uint4, padded rows ----------------
#pragma unroll
        for (int i = 0; i < 4; ++i) {
            const int idx = i * 512 + tid;
            const int row = idx >> 4, c4 = idx & 15;
            const int grow = row0 + row;
            uint4 v = make_uint4(0u, 0u, 0u, 0u);
            if (grow < N) v = ((const uint4*)aggPb)[(size_t)grow * 16 + c4];
            *(uint4*)&As[row * LDA + c4 * 8] = v;
        }
        __syncthreads();

        // ---- Phase A: T = relu(A@W1 + b1) ----------------------------------
        bf16x8 afrag[2][4];
#pragma unroll
        for (int ss = 0; ss < 2; ++ss)
#pragma unroll
            for (int ch = 0; ch < 4; ++ch)
                afrag[ss][ch] = *(const bf16x8*)&As[(rowbase + ss * 16 + m) * LDA + ch * 32 + quad * 8];

        f32x4 acc[2][4];
#pragma unroll
        for (int ss = 0; ss < 2; ++ss)
#pragma unroll
            for (int ct = 0; ct < 4; ++ct) acc[ss][ct] = (f32x4){0.f, 0.f, 0.f, 0.f};

#pragma unroll
        for (int ct = 0; ct < 4; ++ct) {
            bf16x8 bfr[4];
#pragma unroll
            for (int ch = 0; ch < 4; ++ch)
                bfr[ch] = *(const bf16x8*)&W1s[(colbase + ct * 16 + m) * LDA + ch * 32 + quad * 8];
#pragma unroll
            for (int ss = 0; ss < 2; ++ss)
#pragma unroll
                for (int ch = 0; ch < 4; ++ch)
                    acc[ss][ct] = __builtin_amdgcn_mfma_f32_16x16x32_bf16(
                        afrag[ss][ch], bfr[ch], acc[ss][ct], 0, 0, 0);
        }

        // bias + relu -> Ts[row][col] bf16
#pragma unroll
        for (int ss = 0; ss < 2; ++ss)
#pragma unroll
            for (int ct = 0; ct < 4; ++ct)
#pragma unroll
                for (int r = 0; r < 4; ++r) {
                    const float v = fmaxf(acc[ss][ct][r] + b1r[ct], 0.f);
                    const int row = rowbase + ss * 16 + quad * 4 + r;
                    const int col = colbase + ct * 16 + m;
                    Ts[row * LDA + col] = (short)bf16_rne(v);
                }
        __syncthreads();   // T complete; also all As reads done

        // ---- Phase B: C = T @ W2 (each wave: 16 rows x 64 cols) ------------
        const int rb2 = wave * 16;
        bf16x8 tfrag[4];
#pragma unroll
        for (int ch = 0; ch < 4; ++ch)
            tfrag[ch] = *(const bf16x8*)&Ts[(rb2 + m) * LDA + ch * 32 + quad * 8];

        f32x4 acc2[4];
#pragma unroll
        for (int ct = 0; ct < 4; ++ct) acc2[ct] = (f32x4){0.f, 0.f, 0.f, 0.f};
#pragma unroll
        for (int ct = 0; ct < 4; ++ct)
#pragma unroll
            for (int ch = 0; ch < 4; ++ch) {
                const bf16x8 bfr = *(const bf16x8*)&W2s[(ct * 16 + m) * LDA + ch * 32 + quad * 8];
                acc2[ct] = __builtin_amdgcn_mfma_f32_16x16x32_bf16(
                    tfrag[ch], bfr, acc2[ct], 0, 0, 0);
            }

        // ---- C bounce via As (bf16), then coalesced store ------------------
#pragma unroll
        for (int ct = 0; ct < 4; ++ct)
#pragma unroll
            for (int r = 0; r < 4; ++r) {
                const int row = rb2 + quad * 4 + r;
                const int col = ct * 16 + m;
                As[row * LDA + col] = (short)bf16_rne(acc2[ct][r]);
            }
        __syncthreads();
#pragma unroll
        for (int i = 0; i < 2; ++i) {
            const int idx = i * 512 + tid;      // 128 rows x 8 uint4 (64 bf16)
            const int row = idx >> 3, c4 = idx & 7;
            if (row0 + row < N)
                ((uint4*)sup2b)[(size_t)(row0 + row) * 8 + c4] = *(uint4*)&As[row * LDA + c4 * 8];
        }
    }
}

extern "C" void kernel_launch(void* const* d_in, const int* in_sizes, int n_in,
                              void* d_out, int out_size, void* d_ws, size_t ws_size,
                              hipStream_t stream) {
    const float* x  = (const float*)d_in[0];
    const int*   ei = (const int*)d_in[1];   // [2, E]: row 0 = dst, row 1 = src
    const float* ew = (const float*)d_in[2];
    const float* W1 = (const float*)d_in[3];
    const float* b1 = (const float*)d_in[4];
    const float* W2 = (const float*)d_in[5];
    const float* b2 = (const float*)d_in[6];
    float* out = (float*)d_out;

    const int* dstIdx = ei;
    const int* srcIdx = ei + N_EDGES;

    // Workspace (~90 MB):
    //   xb [N*64 uint, 25.6 MB] -> aliased by sup2b
    //   aggPb bf16 [N*64 uint, 25.6 MB]; bucketed aliases it during CSR build
    //   w1tb/w2tb after aggPb; csr_ef [E int2, 12.8 MB]; padded counters after.
    uint32* xb      = (uint32*)d_ws;
    uint32* aggPb   = xb + (size_t)N_NODES * 64;
    uint32* w1tb    = aggPb + (size_t)N_NODES * 64;   // 8192 uint
    uint32* w2tb    = w1tb + 128 * 64;                // 4096 uint
    int2*   csr_ef  = (int2*)(xb + (size_t)N_NODES * 64 + (size_t)N_NODES * 128);
    int*    bktCnt  = (int*)(csr_ef + N_EDGES);   // NB*PAD (padded)
    int*    bCur    = bktCnt + NB * PAD;          // NB*PAD (init by bucket_scan)
    int*    bBase   = bCur + NB * PAD;            // NB+1
    int*    offs    = bBase + NB + 1;             // N+1
    int2*   bucketed = (int2*)aggPb;              // alias (dead before aggPb written)
    uint32* sup2b   = xb;                         // alias (dead before sup2b written)

    // --- zero padded bucket counts ---
    (void)hipMemsetAsync(bktCnt, 0, (size_t)NB * PAD * sizeof(int), stream);
    conv_x<<<(N_NODES * 64 + 255) / 256, 256, 0, stream>>>(x, xb);
    conv_w<<<48, 256, 0, stream>>>(W1, W2, w1tb, w2tb);

    // --- bucketed CSR build ---
    bucket_hist<<<NB, 256, 0, stream>>>(dstIdx, bktCnt);
    bucket_scan<<<1, 512, 0, stream>>>(bktCnt, bBase, bCur, offs);
    bucket_scatter2<<<SC_BLOCKS, 256, 0, stream>>>(dstIdx, srcIdx, ew, bCur, bucketed);
    bucket_csr<<<NB, 256, 0, stream>>>(bucketed, bBase, offs, csr_ef);

    // --- Layer 1 aggregate-first: aggPb = bf16(A @ x) ---
    aggregate<128><<<(N_NODES * 64) / 256, 256, 0, stream>>>(xb, offs, csr_ef,
                                                             nullptr, aggPb);
    // --- Fused transform (MFMA): sup2b = bf16(relu(aggPb@W1 + b1) @ W2) ---
    gemm_fused<<<256, 512, 0, stream>>>(aggPb, w1tb, b1, w2tb, sup2b, N_NODES);

    // --- Layer 2 aggregate (bf16 gather), bias b2 folded in ---
    aggregate<64><<<(N_NODES * 64) / 256, 256, 0, stream>>>(sup2b, offs, csr_ef,
                                                            b2, out);
}